// Round 9
// baseline (146.292 us; speedup 1.0000x reference)
//
#include <hip/hip_runtime.h>
#include <math.h>

#define N_CLASSES 1000
#define FEAT_DIM 1024
#define PROJ_DIM 256
#define BATCH 32
#define NUM_SUPPORT 8192
#define NBLK 512  // gemm_score grid (2 blocks/CU, all co-resident)

// prelude grid layout
#define PW_BLOCKS 16   // prep_w: 64-k tile each
#define PX_BLOCKS 256  // proj_x (32 b x 8 cc)
#define PZ_BLOCKS 256  // zero sc (1 MB) + counter

typedef __attribute__((ext_vector_type(8))) _Float16 f16x8;
typedef __attribute__((ext_vector_type(2))) _Float16 f16x2;
typedef __attribute__((ext_vector_type(4))) float f32x4;

// ---------------------------------------------------------------------------
// Prelude (one dispatch): prep_w (W->fp16 n-major) | proj_x (xqh2=fp16(2xW))
// | zero sc + counter. Branch is uniform per block. prep_a is gone — the GEMM
// now converts sx fp32->fp16 in-register during staging (round-8 lesson:
// prelude's 48 MB prep_a traffic was the biggest remaining own-cost).
// ---------------------------------------------------------------------------
__global__ __launch_bounds__(256) void prelude_kernel(
    const float* __restrict__ W, const float* __restrict__ x,
    _Float16* __restrict__ W1, _Float16* __restrict__ xqh2,
    float* __restrict__ sc, int* __restrict__ counter) {
  __shared__ float part[256];
  __shared__ _Float16 Lw[256][66];  // transpose tile, padded
  const int bid = blockIdx.x;
  const int t = threadIdx.x;

  if (bid < PW_BLOCKS) {
    // ---- prep_w: W (k-major) -> W1 (n-major fp16) via LDS transpose.
    const int k0 = bid * 64;
#pragma unroll 8
    for (int kk = 0; kk < 64; kk++) {
      Lw[t][kk] = (_Float16)W[(size_t)(k0 + kk) * PROJ_DIM + t];
    }
    __syncthreads();
#pragma unroll
    for (int i = 0; i < 8; i++) {
      *(f16x8*)&W1[(size_t)t * FEAT_DIM + k0 + i * 8] = *(f16x8*)&Lw[t][i * 8];
    }
  } else if (bid < PW_BLOCKS + PX_BLOCKS) {
    // ---- proj_x: xqh2[b][col] = fp16(2 * (x@W)[b][col]).
    // (-||xq_b||^2 is constant per row -> cancels in softmax.)
    const int pxb = bid - PW_BLOCKS;
    const int b = pxb >> 3, cc = pxb & 7;
    const int col = t & 31, ks = t >> 5;
    const int gc = cc * 32 + col;
    const int k0 = ks * 128;
    float s = 0.f;
#pragma unroll 8
    for (int k = 0; k < 128; k++) {
      s = fmaf(x[(size_t)b * FEAT_DIM + k0 + k],
               W[(size_t)(k0 + k) * PROJ_DIM + gc], s);
    }
    part[t] = s;
    __syncthreads();
    if (t < 32) {
      float acc = 0.f;
#pragma unroll
      for (int i = 0; i < 8; i++) acc += part[i * 32 + t];
      xqh2[(size_t)b * PROJ_DIM + cc * 32 + t] = (_Float16)(2.0f * acc);
    }
  } else {
    // ---- zero sc (atomicAdd target) + completion counter
    const int zb = bid - PW_BLOCKS - PX_BLOCKS;
    if (zb == 0 && t == 0) *counter = 0;
    float4 z = {0.f, 0.f, 0.f, 0.f};
    *(float4*)&sc[(size_t)zb * 1024 + t * 4] = z;
  }
}

// ---------------------------------------------------------------------------
// gemm_score_finish: 64x64 tile of sxp = fp16(sx) @ W1^T (MFMA, K=1024),
// A staged fp32->fp16 in-register (XOR chunk swizzle c^(row&7) preserved so
// the MFMA read path is unchanged). Fused score epilogue: one atomicAdd per
// (b,j), 4-way XCD-local contention. Then completion-counter finish: the last
// 32 blocks each run one batch row's softmax + class bins + log (spin-free
// deadlock: every block increments before any block waits; 512 blocks are all
// co-resident at 2/CU).
// Grid 512 flat: xcd=bid&7, idx=bid>>3, m-tile=xcd*16+(idx&15), n-tile=idx>>4.
// ---------------------------------------------------------------------------
__global__ __launch_bounds__(256) void gemm_score_finish_kernel(
    const float* __restrict__ sx, const _Float16* __restrict__ W1,
    const _Float16* __restrict__ xqh2, float* __restrict__ sc,
    int* __restrict__ counter, const int* __restrict__ sy,
    float* __restrict__ out) {
  __shared__ _Float16 At[64 * 64];  // staging, XOR-swizzled chunks
  __shared__ _Float16 Bt[64 * 64];
  __shared__ _Float16 Sx[64 * 72];  // sxp tile, padded stride 72
  __shared__ _Float16 Xl[32 * 64];  // 2*xq slice for this n-chunk
  __shared__ float red1[4];
  __shared__ float red2[4];
  __shared__ int ticket_s;

  const int tid = threadIdx.x;
  const int w = tid >> 6;
  const int lane = tid & 63;
  const int xcd = blockIdx.x & 7;
  const int idx = blockIdx.x >> 3;
  const int bm = (xcd * 16 + (idx & 15)) * 64;  // 0..127 m-tiles
  const int bn = (idx >> 4) * 64;               // 0..3 n-tiles
  const int wm = w & 1, wn = w >> 1;
  const int m16 = lane & 15, quad = lane >> 4;
  const int lrow8 = lane >> 3;        // 0..7
  const int gB = (lane & 7) ^ lrow8;  // XOR-swizzled global chunk (B path)

  // load Xl: 32 b-rows x 64 halfs (this block's n-range)
  {
    const int r = tid >> 3, c = tid & 7;
    *(f16x8*)&Xl[r * 64 + c * 8] =
        *(const f16x8*)&xqh2[(size_t)r * PROJ_DIM + bn + c * 8];
  }

  // A staging: lane owns row = w*16 + (lane>>2), chunks cg0, cg0+1 (8 halfs
  // each). Written to LDS position c^(row&7) — MFMA read path unchanged.
  const int arow = w * 16 + (lane >> 2);
  const int cg0 = (lane & 3) * 2;
  const float* __restrict__ abase =
      sx + (size_t)(bm + arow) * FEAT_DIM + cg0 * 8;
  _Float16* __restrict__ ad0 = &At[arow * 64 + ((cg0) ^ (arow & 7)) * 8];
  _Float16* __restrict__ ad1 = &At[arow * 64 + ((cg0 + 1) ^ (arow & 7)) * 8];

  f32x4 acc[2][2];
#pragma unroll
  for (int mt = 0; mt < 2; mt++)
#pragma unroll
    for (int nt = 0; nt < 2; nt++) acc[mt][nt] = (f32x4){0.f, 0.f, 0.f, 0.f};

  for (int kb = 0; kb < FEAT_DIM; kb += 64) {
    // stage A: 16 fp32 -> 16 fp16, two swizzled b128 LDS writes
    {
      const float4* gp = (const float4*)(abase + kb);
      const float4 v0 = gp[0], v1 = gp[1], v2 = gp[2], v3 = gp[3];
      f16x8 h0 = {(_Float16)v0.x, (_Float16)v0.y, (_Float16)v0.z,
                  (_Float16)v0.w, (_Float16)v1.x, (_Float16)v1.y,
                  (_Float16)v1.z, (_Float16)v1.w};
      f16x8 h1 = {(_Float16)v2.x, (_Float16)v2.y, (_Float16)v2.z,
                  (_Float16)v2.w, (_Float16)v3.x, (_Float16)v3.y,
                  (_Float16)v3.z, (_Float16)v3.w};
      *(f16x8*)ad0 = h0;
      *(f16x8*)ad1 = h1;
    }
    // stage B tile (64 n x 64 k fp16): 2 async instrs/wave
#pragma unroll
    for (int i = 0; i < 2; i++) {
      const int nrow = w * 16 + i * 8 + lrow8;
      const _Float16* gp = W1 + (size_t)(bn + nrow) * FEAT_DIM + kb + gB * 8;
      __builtin_amdgcn_global_load_lds(
          (const __attribute__((address_space(1))) void*)gp,
          (__attribute__((address_space(3))) void*)(Bt + (w * 16 + i * 8) * 64),
          16, 0, 0);
    }
    __syncthreads();

#pragma unroll
    for (int s = 0; s < 2; s++) {
      const int slot = (s * 4 + quad) ^ (m16 & 7);
      f16x8 af[2], bf[2];
#pragma unroll
      for (int mt = 0; mt < 2; mt++) {
        const int row = wm * 32 + mt * 16 + m16;
        af[mt] = *(f16x8*)&At[row * 64 + slot * 8];
      }
#pragma unroll
      for (int nt = 0; nt < 2; nt++) {
        const int nrow = wn * 32 + nt * 16 + m16;
        bf[nt] = *(f16x8*)&Bt[nrow * 64 + slot * 8];
      }
#pragma unroll
      for (int mt = 0; mt < 2; mt++)
#pragma unroll
        for (int nt = 0; nt < 2; nt++)
          acc[mt][nt] = __builtin_amdgcn_mfma_f32_16x16x32_f16(
              af[mt], bf[nt], acc[mt][nt], 0, 0, 0);
    }
    __syncthreads();
  }

  // ---- epilogue: sxp tile -> LDS (fp16, padded stride 72).
  // C/D layout: col = lane&15 (n), row = quad*4 + reg (m/j)
#pragma unroll
  for (int mt = 0; mt < 2; mt++)
#pragma unroll
    for (int nt = 0; nt < 2; nt++)
#pragma unroll
      for (int r = 0; r < 4; r++) {
        const int jl = wm * 32 + mt * 16 + quad * 4 + r;
        const int nl = wn * 32 + nt * 16 + m16;
        Sx[jl * 72 + nl] = (_Float16)acc[mt][nt][r];
      }
  __syncthreads();

  // ---- fused partial score: thread t -> j = t&63, b-group = t>>6 (8 b's)
  const int j = tid & 63;
  const int bg = tid >> 6;
  float dotb[8] = {0.f, 0.f, 0.f, 0.f, 0.f, 0.f, 0.f, 0.f};
  float rsq = 0.f;
#pragma unroll
  for (int c = 0; c < 8; c++) {
    const f16x8 hv = *(const f16x8*)&Sx[j * 72 + c * 8];
    const f16x2* hp = (const f16x2*)&hv;
#pragma unroll
    for (int i = 0; i < 4; i++)
      rsq = __builtin_amdgcn_fdot2(hp[i], hp[i], rsq, false);
#pragma unroll
    for (int b8 = 0; b8 < 8; b8++) {
      const f16x8 xv = *(const f16x8*)&Xl[(bg * 8 + b8) * 64 + c * 8];
      const f16x2* xp = (const f16x2*)&xv;
#pragma unroll
      for (int i = 0; i < 4; i++)
        dotb[b8] = __builtin_amdgcn_fdot2(hp[i], xp[i], dotb[b8], false);
    }
  }
#pragma unroll
  for (int b8 = 0; b8 < 8; b8++) {
    atomicAdd(&sc[(size_t)(bg * 8 + b8) * NUM_SUPPORT + bm + j],
              dotb[b8] - rsq);
  }

  // ---- completion ticket (release) ----
  __threadfence();   // my sc atomics visible device-wide
  __syncthreads();   // all 256 threads done
  if (tid == 0) ticket_s = atomicAdd(counter, 1);
  __syncthreads();
  const int tk = ticket_s;
  if (tk < NBLK - BATCH) return;

  // ---- finish: this block owns batch row b ----
  const int b = tk - (NBLK - BATCH);
  if (tid == 0) {
    while (__hip_atomic_load(counter, __ATOMIC_ACQUIRE,
                             __HIP_MEMORY_SCOPE_AGENT) < NBLK) {
    }
  }
  __syncthreads();
  __threadfence();  // acquire: sc fully visible to all threads

  float* cls = (float*)At;  // overlay dead staging LDS (8 KB >= 4 KB)
  for (int c = tid; c < N_CLASSES; c += 256) cls[c] = 0.0f;

  float v[32];
  float m = -1e30f;
#pragma unroll
  for (int jj = 0; jj < 32; jj++) {
    v[jj] = sc[(size_t)b * NUM_SUPPORT + jj * 256 + tid];
    m = fmaxf(m, v[jj]);
  }
#pragma unroll
  for (int o = 1; o < 64; o <<= 1) m = fmaxf(m, __shfl_xor(m, o, 64));
  if (lane == 0) red1[w] = m;
  __syncthreads();  // covers cls zeros + red1
  const float gm = fmaxf(fmaxf(red1[0], red1[1]), fmaxf(red1[2], red1[3]));

  float lsum = 0.0f;
#pragma unroll
  for (int jj = 0; jj < 32; jj++) {
    const float e = expf(v[jj] - gm);
    lsum += e;
    atomicAdd(&cls[sy[jj * 256 + tid]], e);
  }
#pragma unroll
  for (int o = 1; o < 64; o <<= 1) lsum += __shfl_xor(lsum, o, 64);
  if (lane == 0) red2[w] = lsum;
  __syncthreads();
  const float total = (red2[0] + red2[1]) + (red2[2] + red2[3]);
  const float inv = 1.0f / total;
  for (int c = tid; c < N_CLASSES; c += 256) {
    out[(size_t)b * N_CLASSES + c] = logf(cls[c] * inv + 1e-12f);
  }
}

// ---------------------------------------------------------------------------
extern "C" void kernel_launch(void* const* d_in, const int* in_sizes, int n_in,
                              void* d_out, int out_size, void* d_ws,
                              size_t ws_size, hipStream_t stream) {
  const float* x = (const float*)d_in[0];   // (32, 1024)
  const float* sx = (const float*)d_in[1];  // (8192, 1024)
  const float* W = (const float*)d_in[2];   // (1024, 256)
  const int* sy = (const int*)d_in[3];      // (8192,)
  float* out = (float*)d_out;               // (32, 1000)

  char* p = (char*)d_ws;
  float* sc = (float*)p;          p += (size_t)BATCH * NUM_SUPPORT * 4;
  _Float16* W1 = (_Float16*)p;    p += (size_t)PROJ_DIM * FEAT_DIM * 2;
  _Float16* xqh2 = (_Float16*)p;  p += (size_t)BATCH * PROJ_DIM * 2;
  int* counter = (int*)p;

  prelude_kernel<<<dim3(PW_BLOCKS + PX_BLOCKS + PZ_BLOCKS), dim3(256), 0,
                   stream>>>(W, x, W1, xqh2, sc, counter);
  gemm_score_finish_kernel<<<dim3(NBLK), dim3(256), 0, stream>>>(
      sx, W1, xqh2, sc, counter, sy, out);
}

// Round 10
// 114.855 us; speedup vs baseline: 1.2737x; 1.2737x over previous
//
#include <hip/hip_runtime.h>
#include <math.h>

#define N_CLASSES 1000
#define FEAT_DIM 1024
#define PROJ_DIM 256
#define BATCH 32
#define NUM_SUPPORT 8192

// prelude grid layout (prep_a deleted: A is converted in-GEMM from fp32 sx)
#define PW_BLOCKS 16   // prep_w: 64-k tile each
#define PX_BLOCKS 256  // proj_x (32 b x 8 cc)
#define PZ_BLOCKS 256  // zero sc (1 MB)

typedef __attribute__((ext_vector_type(8))) _Float16 f16x8;
typedef __attribute__((ext_vector_type(2))) _Float16 f16x2;
typedef __attribute__((ext_vector_type(4))) float f32x4;

// ---------------------------------------------------------------------------
// Prelude (one dispatch): prep_w (W->fp16 n-major) | proj_x (xqh2=fp16(2xW))
// | zero sc. Branch is uniform per block.
// (-||xq_b||^2 is constant per batch row -> cancels in softmax.)
// ---------------------------------------------------------------------------
__global__ __launch_bounds__(256) void prelude_kernel(
    const float* __restrict__ W, const float* __restrict__ x,
    _Float16* __restrict__ W1, _Float16* __restrict__ xqh2,
    float* __restrict__ sc) {
  __shared__ float part[256];
  __shared__ _Float16 Lw[256][66];  // transpose tile, padded
  const int bid = blockIdx.x;
  const int t = threadIdx.x;

  if (bid < PW_BLOCKS) {
    // ---- prep_w: W (k-major) -> W1 (n-major fp16) via LDS transpose.
    const int k0 = bid * 64;
#pragma unroll 8
    for (int kk = 0; kk < 64; kk++) {
      Lw[t][kk] = (_Float16)W[(size_t)(k0 + kk) * PROJ_DIM + t];
    }
    __syncthreads();
#pragma unroll
    for (int i = 0; i < 8; i++) {
      *(f16x8*)&W1[(size_t)t * FEAT_DIM + k0 + i * 8] = *(f16x8*)&Lw[t][i * 8];
    }
  } else if (bid < PW_BLOCKS + PX_BLOCKS) {
    // ---- proj_x: xqh2[b][col] = fp16(2 * (x@W)[b][col])
    const int pxb = bid - PW_BLOCKS;
    const int b = pxb >> 3, cc = pxb & 7;
    const int col = t & 31, ks = t >> 5;
    const int gc = cc * 32 + col;
    const int k0 = ks * 128;
    float s = 0.f;
#pragma unroll 8
    for (int k = 0; k < 128; k++) {
      s = fmaf(x[(size_t)b * FEAT_DIM + k0 + k],
               W[(size_t)(k0 + k) * PROJ_DIM + gc], s);
    }
    part[t] = s;
    __syncthreads();
    if (t < 32) {
      float acc = 0.f;
#pragma unroll
      for (int i = 0; i < 8; i++) acc += part[i * 32 + t];
      xqh2[(size_t)b * PROJ_DIM + cc * 32 + t] = (_Float16)(2.0f * acc);
    }
  } else {
    // ---- zero sc (atomicAdd target; ws is re-poisoned every launch)
    const int zb = bid - PW_BLOCKS - PX_BLOCKS;
    float4 z = {0.f, 0.f, 0.f, 0.f};
    *(float4*)&sc[(size_t)zb * 1024 + t * 4] = z;
  }
}

// ---------------------------------------------------------------------------
// gemm_score: 64x64 tile of sxp = fp16(sx) @ W1^T (MFMA, K=1024).
// A is staged fp32->fp16 in-register (XOR chunk swizzle c^(row&7) preserved
// so the MFMA read path is unchanged). Fused score epilogue: one atomicAdd
// per (b,j), 4-way XCD-local contention (round-5 lesson). sxp never hits
// global memory. NO spin/ticket finish (round-9 lesson: the fused
// completion-counter tail showed a ~80 µs low-occupancy stall signature).
// Grid 512 flat: xcd=bid&7, idx=bid>>3, m-tile=xcd*16+(idx&15), n-tile=idx>>4
// -> all 4 n-tiles of one m-tile on one XCD.
// ---------------------------------------------------------------------------
__global__ __launch_bounds__(256) void gemm_score_kernel(
    const float* __restrict__ sx, const _Float16* __restrict__ W1,
    const _Float16* __restrict__ xqh2, float* __restrict__ sc) {
  __shared__ _Float16 At[64 * 64];  // staging, XOR-swizzled chunks
  __shared__ _Float16 Bt[64 * 64];
  __shared__ _Float16 Sx[64 * 72];  // sxp tile, padded stride 72
  __shared__ _Float16 Xl[32 * 64];  // 2*xq slice for this n-chunk

  const int tid = threadIdx.x;
  const int w = tid >> 6;
  const int lane = tid & 63;
  const int xcd = blockIdx.x & 7;
  const int idx = blockIdx.x >> 3;
  const int bm = (xcd * 16 + (idx & 15)) * 64;  // 0..127 m-tiles
  const int bn = (idx >> 4) * 64;               // 0..3 n-tiles
  const int wm = w & 1, wn = w >> 1;
  const int m16 = lane & 15, quad = lane >> 4;
  const int lrow8 = lane >> 3;        // 0..7
  const int gB = (lane & 7) ^ lrow8;  // XOR-swizzled global chunk (B path)

  // load Xl: 32 b-rows x 64 halfs (this block's n-range)
  {
    const int r = tid >> 3, c = tid & 7;
    *(f16x8*)&Xl[r * 64 + c * 8] =
        *(const f16x8*)&xqh2[(size_t)r * PROJ_DIM + bn + c * 8];
  }

  // A staging: lane owns row = w*16 + (lane>>2), chunks cg0, cg0+1 (8 halfs
  // each). Written to LDS position c^(row&7) — MFMA read path unchanged.
  const int arow = w * 16 + (lane >> 2);
  const int cg0 = (lane & 3) * 2;
  const float* __restrict__ abase =
      sx + (size_t)(bm + arow) * FEAT_DIM + cg0 * 8;
  _Float16* __restrict__ ad0 = &At[arow * 64 + ((cg0) ^ (arow & 7)) * 8];
  _Float16* __restrict__ ad1 = &At[arow * 64 + ((cg0 + 1) ^ (arow & 7)) * 8];

  f32x4 acc[2][2];
#pragma unroll
  for (int mt = 0; mt < 2; mt++)
#pragma unroll
    for (int nt = 0; nt < 2; nt++) acc[mt][nt] = (f32x4){0.f, 0.f, 0.f, 0.f};

  for (int kb = 0; kb < FEAT_DIM; kb += 64) {
    // stage A: 16 fp32 -> 16 fp16, two swizzled b128 LDS writes
    {
      const float4* gp = (const float4*)(abase + kb);
      const float4 v0 = gp[0], v1 = gp[1], v2 = gp[2], v3 = gp[3];
      f16x8 h0 = {(_Float16)v0.x, (_Float16)v0.y, (_Float16)v0.z,
                  (_Float16)v0.w, (_Float16)v1.x, (_Float16)v1.y,
                  (_Float16)v1.z, (_Float16)v1.w};
      f16x8 h1 = {(_Float16)v2.x, (_Float16)v2.y, (_Float16)v2.z,
                  (_Float16)v2.w, (_Float16)v3.x, (_Float16)v3.y,
                  (_Float16)v3.z, (_Float16)v3.w};
      *(f16x8*)ad0 = h0;
      *(f16x8*)ad1 = h1;
    }
    // stage B tile (64 n x 64 k fp16): 2 async instrs/wave
#pragma unroll
    for (int i = 0; i < 2; i++) {
      const int nrow = w * 16 + i * 8 + lrow8;
      const _Float16* gp = W1 + (size_t)(bn + nrow) * FEAT_DIM + kb + gB * 8;
      __builtin_amdgcn_global_load_lds(
          (const __attribute__((address_space(1))) void*)gp,
          (__attribute__((address_space(3))) void*)(Bt + (w * 16 + i * 8) * 64),
          16, 0, 0);
    }
    __syncthreads();

#pragma unroll
    for (int s = 0; s < 2; s++) {
      const int slot = (s * 4 + quad) ^ (m16 & 7);
      f16x8 af[2], bf[2];
#pragma unroll
      for (int mt = 0; mt < 2; mt++) {
        const int row = wm * 32 + mt * 16 + m16;
        af[mt] = *(f16x8*)&At[row * 64 + slot * 8];
      }
#pragma unroll
      for (int nt = 0; nt < 2; nt++) {
        const int nrow = wn * 32 + nt * 16 + m16;
        bf[nt] = *(f16x8*)&Bt[nrow * 64 + slot * 8];
      }
#pragma unroll
      for (int mt = 0; mt < 2; mt++)
#pragma unroll
        for (int nt = 0; nt < 2; nt++)
          acc[mt][nt] = __builtin_amdgcn_mfma_f32_16x16x32_f16(
              af[mt], bf[nt], acc[mt][nt], 0, 0, 0);
    }
    __syncthreads();
  }

  // ---- epilogue: sxp tile -> LDS (fp16, padded stride 72).
  // C/D layout: col = lane&15 (n), row = quad*4 + reg (m/j)
#pragma unroll
  for (int mt = 0; mt < 2; mt++)
#pragma unroll
    for (int nt = 0; nt < 2; nt++)
#pragma unroll
      for (int r = 0; r < 4; r++) {
        const int jl = wm * 32 + mt * 16 + quad * 4 + r;
        const int nl = wn * 32 + nt * 16 + m16;
        Sx[jl * 72 + nl] = (_Float16)acc[mt][nt][r];
      }
  __syncthreads();

  // ---- fused partial score: thread t -> j = t&63, b-group = t>>6 (8 b's).
  // Whole wave shares b-group -> Xl reads are same-address broadcasts.
  const int j = tid & 63;
  const int bg = tid >> 6;
  float dotb[8] = {0.f, 0.f, 0.f, 0.f, 0.f, 0.f, 0.f, 0.f};
  float rsq = 0.f;
#pragma unroll
  for (int c = 0; c < 8; c++) {
    const f16x8 hv = *(const f16x8*)&Sx[j * 72 + c * 8];
    const f16x2* hp = (const f16x2*)&hv;
#pragma unroll
    for (int i = 0; i < 4; i++)
      rsq = __builtin_amdgcn_fdot2(hp[i], hp[i], rsq, false);
#pragma unroll
    for (int b8 = 0; b8 < 8; b8++) {
      const f16x8 xv = *(const f16x8*)&Xl[(bg * 8 + b8) * 64 + c * 8];
      const f16x2* xp = (const f16x2*)&xv;
#pragma unroll
      for (int i = 0; i < 4; i++)
        dotb[b8] = __builtin_amdgcn_fdot2(hp[i], xp[i], dotb[b8], false);
    }
  }
#pragma unroll
  for (int b8 = 0; b8 < 8; b8++) {
    atomicAdd(&sc[(size_t)(bg * 8 + b8) * NUM_SUPPORT + bm + j],
              dotb[b8] - rsq);
  }
}

// ---------------------------------------------------------------------------
// finish: per batch row: row max (in-kernel), exp, class bins, log.
// One block (1024 thr) per b; row values kept in registers between passes.
// ---------------------------------------------------------------------------
__global__ __launch_bounds__(1024) void finish_kernel(
    const float* __restrict__ sc, const int* __restrict__ sy,
    float* __restrict__ out) {
  __shared__ float cls[N_CLASSES];
  __shared__ float redm[16];
  __shared__ float reds[16];

  const int b = blockIdx.x;
  const int t = threadIdx.x;
  const int lane = t & 63, wave = t >> 6;

  float v[8];
  float m = -1e30f;
#pragma unroll
  for (int jj = 0; jj < 8; jj++) {
    v[jj] = sc[(size_t)b * NUM_SUPPORT + jj * 1024 + t];
    m = fmaxf(m, v[jj]);
  }
#pragma unroll
  for (int o = 1; o < 64; o <<= 1) m = fmaxf(m, __shfl_xor(m, o, 64));
  if (lane == 0) redm[wave] = m;
  if (t < N_CLASSES) cls[t] = 0.0f;
  __syncthreads();
  float gm = redm[0];
#pragma unroll
  for (int i = 1; i < 16; i++) gm = fmaxf(gm, redm[i]);

  float lsum = 0.0f;
#pragma unroll
  for (int jj = 0; jj < 8; jj++) {
    const float e = expf(v[jj] - gm);
    lsum += e;
    atomicAdd(&cls[sy[jj * 1024 + t]], e);
  }
#pragma unroll
  for (int o = 1; o < 64; o <<= 1) lsum += __shfl_xor(lsum, o, 64);
  if (lane == 0) reds[wave] = lsum;
  __syncthreads();
  float total = 0.f;
#pragma unroll
  for (int i = 0; i < 16; i++) total += reds[i];
  const float inv = 1.0f / total;
  if (t < N_CLASSES) {
    out[(size_t)b * N_CLASSES + t] = logf(cls[t] * inv + 1e-12f);
  }
}

// ---------------------------------------------------------------------------
extern "C" void kernel_launch(void* const* d_in, const int* in_sizes, int n_in,
                              void* d_out, int out_size, void* d_ws,
                              size_t ws_size, hipStream_t stream) {
  const float* x = (const float*)d_in[0];   // (32, 1024)
  const float* sx = (const float*)d_in[1];  // (8192, 1024)
  const float* W = (const float*)d_in[2];   // (1024, 256)
  const int* sy = (const int*)d_in[3];      // (8192,)
  float* out = (float*)d_out;               // (32, 1000)

  char* p = (char*)d_ws;
  float* sc = (float*)p;          p += (size_t)BATCH * NUM_SUPPORT * 4;
  _Float16* W1 = (_Float16*)p;    p += (size_t)PROJ_DIM * FEAT_DIM * 2;
  _Float16* xqh2 = (_Float16*)p;  // 32*256*2

  prelude_kernel<<<dim3(PW_BLOCKS + PX_BLOCKS + PZ_BLOCKS), dim3(256), 0,
                   stream>>>(W, x, W1, xqh2, sc);
  gemm_score_kernel<<<dim3(512), dim3(256), 0, stream>>>(sx, W1, xqh2, sc);
  finish_kernel<<<dim3(BATCH), dim3(1024), 0, stream>>>(sc, sy, out);
}

// Round 11
// 111.296 us; speedup vs baseline: 1.3144x; 1.0320x over previous
//
#include <hip/hip_runtime.h>
#include <math.h>

#define N_CLASSES 1000
#define FEAT_DIM 1024
#define PROJ_DIM 256
#define BATCH 32
#define NUM_SUPPORT 8192

// prelude grid layout (prep_a deleted: A is converted in-GEMM from fp32 sx)
#define PW_BLOCKS 16   // prep_w: 64-k tile each
#define PX_BLOCKS 256  // proj_x (32 b x 8 cc)
#define PZ_BLOCKS 256  // zero sc (1 MB)

typedef __attribute__((ext_vector_type(8))) _Float16 f16x8;
typedef __attribute__((ext_vector_type(2))) _Float16 f16x2;
typedef __attribute__((ext_vector_type(4))) float f32x4;

// ---------------------------------------------------------------------------
// Prelude (one dispatch): prep_w (W->fp16 n-major) | proj_x (xqh2=fp16(2xW))
// | zero sc. Branch is uniform per block.
// (-||xq_b||^2 is constant per batch row -> cancels in softmax.)
// ---------------------------------------------------------------------------
__global__ __launch_bounds__(256) void prelude_kernel(
    const float* __restrict__ W, const float* __restrict__ x,
    _Float16* __restrict__ W1, _Float16* __restrict__ xqh2,
    float* __restrict__ sc) {
  __shared__ float part[256];
  __shared__ _Float16 Lw[256][66];  // transpose tile, padded
  const int bid = blockIdx.x;
  const int t = threadIdx.x;

  if (bid < PW_BLOCKS) {
    // ---- prep_w: W (k-major) -> W1 (n-major fp16) via LDS transpose.
    const int k0 = bid * 64;
#pragma unroll 8
    for (int kk = 0; kk < 64; kk++) {
      Lw[t][kk] = (_Float16)W[(size_t)(k0 + kk) * PROJ_DIM + t];
    }
    __syncthreads();
#pragma unroll
    for (int i = 0; i < 8; i++) {
      *(f16x8*)&W1[(size_t)t * FEAT_DIM + k0 + i * 8] = *(f16x8*)&Lw[t][i * 8];
    }
  } else if (bid < PW_BLOCKS + PX_BLOCKS) {
    // ---- proj_x: xqh2[b][col] = fp16(2 * (x@W)[b][col])
    const int pxb = bid - PW_BLOCKS;
    const int b = pxb >> 3, cc = pxb & 7;
    const int col = t & 31, ks = t >> 5;
    const int gc = cc * 32 + col;
    const int k0 = ks * 128;
    float s = 0.f;
#pragma unroll 8
    for (int k = 0; k < 128; k++) {
      s = fmaf(x[(size_t)b * FEAT_DIM + k0 + k],
               W[(size_t)(k0 + k) * PROJ_DIM + gc], s);
    }
    part[t] = s;
    __syncthreads();
    if (t < 32) {
      float acc = 0.f;
#pragma unroll
      for (int i = 0; i < 8; i++) acc += part[i * 32 + t];
      xqh2[(size_t)b * PROJ_DIM + cc * 32 + t] = (_Float16)(2.0f * acc);
    }
  } else {
    // ---- zero sc (atomicAdd target; ws is re-poisoned every launch)
    const int zb = bid - PW_BLOCKS - PX_BLOCKS;
    float4 z = {0.f, 0.f, 0.f, 0.f};
    *(float4*)&sc[(size_t)zb * 1024 + t * 4] = z;
  }
}

// ---------------------------------------------------------------------------
// gemm_score: 32x64 tile of sxp = fp16(sx) @ W1^T (MFMA, K=1024).
// Round-10 change: m-tile 64 -> 32 rows, grid 512 -> 1024 = 4 blocks/CU
// (was 2) to hide the per-iteration barrier drain (round-3 lesson). All else
// preserved: in-register fp32->fp16 A staging with XOR chunk swizzle
// c^(row&7); fused score epilogue with one atomicAdd per (b,j), 4-way
// XCD-local contention (round-5 lesson); NO spin/ticket finish (round-9).
// Grid 1024 flat: xcd=bid&7, idx=bid>>3, m-tile=xcd*32+(idx&31) (32 rows),
// n-tile=idx>>5 -> all 4 n-tiles of one m-tile on one XCD.
// ---------------------------------------------------------------------------
__global__ __launch_bounds__(256) void gemm_score_kernel(
    const float* __restrict__ sx, const _Float16* __restrict__ W1,
    const _Float16* __restrict__ xqh2, float* __restrict__ sc) {
  __shared__ _Float16 At[32 * 64];  // staging, XOR-swizzled chunks
  __shared__ _Float16 Bt[64 * 64];
  __shared__ _Float16 Sx[32 * 72];  // sxp tile, padded stride 72
  __shared__ _Float16 Xl[32 * 64];  // 2*xq slice for this n-chunk

  const int tid = threadIdx.x;
  const int w = tid >> 6;
  const int lane = tid & 63;
  const int xcd = blockIdx.x & 7;
  const int idx = blockIdx.x >> 3;
  const int bm = (xcd * 32 + (idx & 31)) * 32;  // 0..255 m-tiles of 32 rows
  const int bn = (idx >> 5) * 64;               // 0..3 n-tiles
  const int wm = w & 1, wn = w >> 1;
  const int m16 = lane & 15, quad = lane >> 4;
  const int lrow8 = lane >> 3;        // 0..7
  const int gB = (lane & 7) ^ lrow8;  // XOR-swizzled global chunk (B path)

  // load Xl: 32 b-rows x 64 halfs (this block's n-range)
  {
    const int r = tid >> 3, c = tid & 7;
    *(f16x8*)&Xl[r * 64 + c * 8] =
        *(const f16x8*)&xqh2[(size_t)r * PROJ_DIM + bn + c * 8];
  }

  // A staging: thread owns row = tid>>3 (0..31), chunk c = tid&7 (8 halfs =
  // 8 fp32). Written to LDS position c^(row&7) — MFMA read path unchanged.
  const int arow = tid >> 3;
  const int ac = tid & 7;
  const float* __restrict__ abase =
      sx + (size_t)(bm + arow) * FEAT_DIM + ac * 8;
  _Float16* __restrict__ ad = &At[arow * 64 + (ac ^ (arow & 7)) * 8];

  f32x4 acc[2];
#pragma unroll
  for (int nt = 0; nt < 2; nt++) acc[nt] = (f32x4){0.f, 0.f, 0.f, 0.f};

  for (int kb = 0; kb < FEAT_DIM; kb += 64) {
    // stage A: 8 fp32 -> 8 fp16, one swizzled b128 LDS write
    {
      const float4* gp = (const float4*)(abase + kb);
      const float4 v0 = gp[0], v1 = gp[1];
      f16x8 h0 = {(_Float16)v0.x, (_Float16)v0.y, (_Float16)v0.z,
                  (_Float16)v0.w, (_Float16)v1.x, (_Float16)v1.y,
                  (_Float16)v1.z, (_Float16)v1.w};
      *(f16x8*)ad = h0;
    }
    // stage B tile (64 n x 64 k fp16): 2 async instrs/wave
#pragma unroll
    for (int i = 0; i < 2; i++) {
      const int nrow = w * 16 + i * 8 + lrow8;
      const _Float16* gp = W1 + (size_t)(bn + nrow) * FEAT_DIM + kb + gB * 8;
      __builtin_amdgcn_global_load_lds(
          (const __attribute__((address_space(1))) void*)gp,
          (__attribute__((address_space(3))) void*)(Bt + (w * 16 + i * 8) * 64),
          16, 0, 0);
    }
    __syncthreads();

#pragma unroll
    for (int s = 0; s < 2; s++) {
      const int slot = (s * 4 + quad) ^ (m16 & 7);
      f16x8 af, bf[2];
      {
        const int row = wm * 16 + m16;
        af = *(f16x8*)&At[row * 64 + slot * 8];
      }
#pragma unroll
      for (int nt = 0; nt < 2; nt++) {
        const int nrow = wn * 32 + nt * 16 + m16;
        bf[nt] = *(f16x8*)&Bt[nrow * 64 + slot * 8];
      }
#pragma unroll
      for (int nt = 0; nt < 2; nt++)
        acc[nt] = __builtin_amdgcn_mfma_f32_16x16x32_f16(af, bf[nt], acc[nt],
                                                         0, 0, 0);
    }
    __syncthreads();
  }

  // ---- epilogue: sxp tile -> LDS (fp16, padded stride 72).
  // C/D layout: col = lane&15 (n), row = quad*4 + reg (m/j)
#pragma unroll
  for (int nt = 0; nt < 2; nt++)
#pragma unroll
    for (int r = 0; r < 4; r++) {
      const int jl = wm * 16 + quad * 4 + r;
      const int nl = wn * 32 + nt * 16 + m16;
      Sx[jl * 72 + nl] = (_Float16)acc[nt][r];
    }
  __syncthreads();

  // ---- fused partial score: thread t -> j = t&31, b-group = t>>5 (4 b's).
  // Half-wave shares b-group -> Xl reads are 2-address broadcasts (free).
  const int j = tid & 31;
  const int bg = tid >> 5;
  float dotb[4] = {0.f, 0.f, 0.f, 0.f};
  float rsq = 0.f;
#pragma unroll
  for (int c = 0; c < 8; c++) {
    const f16x8 hv = *(const f16x8*)&Sx[j * 72 + c * 8];
    const f16x2* hp = (const f16x2*)&hv;
#pragma unroll
    for (int i = 0; i < 4; i++)
      rsq = __builtin_amdgcn_fdot2(hp[i], hp[i], rsq, false);
#pragma unroll
    for (int b4 = 0; b4 < 4; b4++) {
      const f16x8 xv = *(const f16x8*)&Xl[(bg * 4 + b4) * 64 + c * 8];
      const f16x2* xp = (const f16x2*)&xv;
#pragma unroll
      for (int i = 0; i < 4; i++)
        dotb[b4] = __builtin_amdgcn_fdot2(hp[i], xp[i], dotb[b4], false);
    }
  }
#pragma unroll
  for (int b4 = 0; b4 < 4; b4++) {
    atomicAdd(&sc[(size_t)(bg * 4 + b4) * NUM_SUPPORT + bm + j],
              dotb[b4] - rsq);
  }
}

// ---------------------------------------------------------------------------
// finish: per batch row: row max (in-kernel), exp, class bins, log.
// One block (1024 thr) per b; row values kept in registers between passes.
// ---------------------------------------------------------------------------
__global__ __launch_bounds__(1024) void finish_kernel(
    const float* __restrict__ sc, const int* __restrict__ sy,
    float* __restrict__ out) {
  __shared__ float cls[N_CLASSES];
  __shared__ float redm[16];
  __shared__ float reds[16];

  const int b = blockIdx.x;
  const int t = threadIdx.x;
  const int lane = t & 63, wave = t >> 6;

  float v[8];
  float m = -1e30f;
#pragma unroll
  for (int jj = 0; jj < 8; jj++) {
    v[jj] = sc[(size_t)b * NUM_SUPPORT + jj * 1024 + t];
    m = fmaxf(m, v[jj]);
  }
#pragma unroll
  for (int o = 1; o < 64; o <<= 1) m = fmaxf(m, __shfl_xor(m, o, 64));
  if (lane == 0) redm[wave] = m;
  if (t < N_CLASSES) cls[t] = 0.0f;
  __syncthreads();
  float gm = redm[0];
#pragma unroll
  for (int i = 1; i < 16; i++) gm = fmaxf(gm, redm[i]);

  float lsum = 0.0f;
#pragma unroll
  for (int jj = 0; jj < 8; jj++) {
    const float e = expf(v[jj] - gm);
    lsum += e;
    atomicAdd(&cls[sy[jj * 1024 + t]], e);
  }
#pragma unroll
  for (int o = 1; o < 64; o <<= 1) lsum += __shfl_xor(lsum, o, 64);
  if (lane == 0) reds[wave] = lsum;
  __syncthreads();
  float total = 0.f;
#pragma unroll
  for (int i = 0; i < 16; i++) total += reds[i];
  const float inv = 1.0f / total;
  if (t < N_CLASSES) {
    out[(size_t)b * N_CLASSES + t] = logf(cls[t] * inv + 1e-12f);
  }
}

// ---------------------------------------------------------------------------
extern "C" void kernel_launch(void* const* d_in, const int* in_sizes, int n_in,
                              void* d_out, int out_size, void* d_ws,
                              size_t ws_size, hipStream_t stream) {
  const float* x = (const float*)d_in[0];   // (32, 1024)
  const float* sx = (const float*)d_in[1];  // (8192, 1024)
  const float* W = (const float*)d_in[2];   // (1024, 256)
  const int* sy = (const int*)d_in[3];      // (8192,)
  float* out = (float*)d_out;               // (32, 1000)

  char* p = (char*)d_ws;
  float* sc = (float*)p;          p += (size_t)BATCH * NUM_SUPPORT * 4;
  _Float16* W1 = (_Float16*)p;    p += (size_t)PROJ_DIM * FEAT_DIM * 2;
  _Float16* xqh2 = (_Float16*)p;  // 32*256*2

  prelude_kernel<<<dim3(PW_BLOCKS + PX_BLOCKS + PZ_BLOCKS), dim3(256), 0,
                   stream>>>(W, x, W1, xqh2, sc);
  gemm_score_kernel<<<dim3(1024), dim3(256), 0, stream>>>(sx, W1, xqh2, sc);
  finish_kernel<<<dim3(BATCH), dim3(1024), 0, stream>>>(sc, sy, out);
}

// Round 12
// 111.147 us; speedup vs baseline: 1.3162x; 1.0013x over previous
//
#include <hip/hip_runtime.h>
#include <math.h>

#define N_CLASSES 1000
#define FEAT_DIM 1024
#define PROJ_DIM 256
#define BATCH 32
#define NUM_SUPPORT 8192

// prelude grid layout (prep_a deleted; sc-zero deleted: partial buffers are
// write-once so no zeroing needed)
#define PW_BLOCKS 16   // prep_w: 64-k tile each
#define PX_BLOCKS 256  // proj_x (32 b x 8 cc)

typedef __attribute__((ext_vector_type(8))) _Float16 f16x8;
typedef __attribute__((ext_vector_type(2))) _Float16 f16x2;
typedef __attribute__((ext_vector_type(4))) float f32x4;

// ---------------------------------------------------------------------------
// Prelude (one dispatch): prep_w (W->fp16 n-major) | proj_x (xqh2=fp16(2xW)).
// Branch is uniform per block.
// (-||xq_b||^2 is constant per batch row -> cancels in softmax.)
// ---------------------------------------------------------------------------
__global__ __launch_bounds__(256) void prelude_kernel(
    const float* __restrict__ W, const float* __restrict__ x,
    _Float16* __restrict__ W1, _Float16* __restrict__ xqh2) {
  __shared__ float part[256];
  __shared__ _Float16 Lw[256][66];  // transpose tile, padded
  const int bid = blockIdx.x;
  const int t = threadIdx.x;

  if (bid < PW_BLOCKS) {
    // ---- prep_w: W (k-major) -> W1 (n-major fp16) via LDS transpose.
    const int k0 = bid * 64;
#pragma unroll 8
    for (int kk = 0; kk < 64; kk++) {
      Lw[t][kk] = (_Float16)W[(size_t)(k0 + kk) * PROJ_DIM + t];
    }
    __syncthreads();
#pragma unroll
    for (int i = 0; i < 8; i++) {
      *(f16x8*)&W1[(size_t)t * FEAT_DIM + k0 + i * 8] = *(f16x8*)&Lw[t][i * 8];
    }
  } else {
    // ---- proj_x: xqh2[b][col] = fp16(2 * (x@W)[b][col])
    const int pxb = bid - PW_BLOCKS;
    const int b = pxb >> 3, cc = pxb & 7;
    const int col = t & 31, ks = t >> 5;
    const int gc = cc * 32 + col;
    const int k0 = ks * 128;
    float s = 0.f;
#pragma unroll 8
    for (int k = 0; k < 128; k++) {
      s = fmaf(x[(size_t)b * FEAT_DIM + k0 + k],
               W[(size_t)(k0 + k) * PROJ_DIM + gc], s);
    }
    part[t] = s;
    __syncthreads();
    if (t < 32) {
      float acc = 0.f;
#pragma unroll
      for (int i = 0; i < 8; i++) acc += part[i * 32 + t];
      xqh2[(size_t)b * PROJ_DIM + cc * 32 + t] = (_Float16)(2.0f * acc);
    }
  }
}

// ---------------------------------------------------------------------------
// gemm_score: 32x64 tile of sxp = fp16(sx) @ W1^T (MFMA, K=1024), 4 blocks/CU
// (round-10/11 lesson). In-register fp32->fp16 A staging with XOR chunk
// swizzle c^(row&7). Fused score epilogue now writes WRITE-ONCE partials:
// scP[ntile][b][j] — no atomics, no zero-init (round-11 change; round-5
// lesson said contended atomics serialize, round-6 lesson says keep the
// partial combine traffic small: 4 MB here, not 256 MB).
// Grid 1024 flat: xcd=bid&7, idx=bid>>3, m-tile=xcd*32+(idx&31) (32 rows),
// n-tile=idx>>5 -> all 4 n-tiles of one m-tile on one XCD (A L2-resident).
// ---------------------------------------------------------------------------
__global__ __launch_bounds__(256) void gemm_score_kernel(
    const float* __restrict__ sx, const _Float16* __restrict__ W1,
    const _Float16* __restrict__ xqh2, float* __restrict__ scP) {
  __shared__ _Float16 At[32 * 64];  // staging, XOR-swizzled chunks
  __shared__ _Float16 Bt[64 * 64];
  __shared__ _Float16 Sx[32 * 72];  // sxp tile, padded stride 72
  __shared__ _Float16 Xl[32 * 64];  // 2*xq slice for this n-chunk

  const int tid = threadIdx.x;
  const int w = tid >> 6;
  const int lane = tid & 63;
  const int xcd = blockIdx.x & 7;
  const int idx = blockIdx.x >> 3;
  const int bm = (xcd * 32 + (idx & 31)) * 32;  // 0..255 m-tiles of 32 rows
  const int ntile = idx >> 5;                   // 0..3
  const int bn = ntile * 64;
  const int wm = w & 1, wn = w >> 1;
  const int m16 = lane & 15, quad = lane >> 4;
  const int lrow8 = lane >> 3;        // 0..7
  const int gB = (lane & 7) ^ lrow8;  // XOR-swizzled global chunk (B path)

  // load Xl: 32 b-rows x 64 halfs (this block's n-range)
  {
    const int r = tid >> 3, c = tid & 7;
    *(f16x8*)&Xl[r * 64 + c * 8] =
        *(const f16x8*)&xqh2[(size_t)r * PROJ_DIM + bn + c * 8];
  }

  // A staging: thread owns row = tid>>3 (0..31), chunk c = tid&7 (8 halfs =
  // 8 fp32). Written to LDS position c^(row&7) — MFMA read path unchanged.
  const int arow = tid >> 3;
  const int ac = tid & 7;
  const float* __restrict__ abase =
      sx + (size_t)(bm + arow) * FEAT_DIM + ac * 8;
  _Float16* __restrict__ ad = &At[arow * 64 + (ac ^ (arow & 7)) * 8];

  f32x4 acc[2];
#pragma unroll
  for (int nt = 0; nt < 2; nt++) acc[nt] = (f32x4){0.f, 0.f, 0.f, 0.f};

  for (int kb = 0; kb < FEAT_DIM; kb += 64) {
    // stage A: 8 fp32 -> 8 fp16, one swizzled b128 LDS write
    {
      const float4* gp = (const float4*)(abase + kb);
      const float4 v0 = gp[0], v1 = gp[1];
      f16x8 h0 = {(_Float16)v0.x, (_Float16)v0.y, (_Float16)v0.z,
                  (_Float16)v0.w, (_Float16)v1.x, (_Float16)v1.y,
                  (_Float16)v1.z, (_Float16)v1.w};
      *(f16x8*)ad = h0;
    }
    // stage B tile (64 n x 64 k fp16): 2 async instrs/wave
#pragma unroll
    for (int i = 0; i < 2; i++) {
      const int nrow = w * 16 + i * 8 + lrow8;
      const _Float16* gp = W1 + (size_t)(bn + nrow) * FEAT_DIM + kb + gB * 8;
      __builtin_amdgcn_global_load_lds(
          (const __attribute__((address_space(1))) void*)gp,
          (__attribute__((address_space(3))) void*)(Bt + (w * 16 + i * 8) * 64),
          16, 0, 0);
    }
    __syncthreads();

#pragma unroll
    for (int s = 0; s < 2; s++) {
      const int slot = (s * 4 + quad) ^ (m16 & 7);
      f16x8 af, bf[2];
      {
        const int row = wm * 16 + m16;
        af = *(f16x8*)&At[row * 64 + slot * 8];
      }
#pragma unroll
      for (int nt = 0; nt < 2; nt++) {
        const int nrow = wn * 32 + nt * 16 + m16;
        bf[nt] = *(f16x8*)&Bt[nrow * 64 + slot * 8];
      }
#pragma unroll
      for (int nt = 0; nt < 2; nt++)
        acc[nt] = __builtin_amdgcn_mfma_f32_16x16x32_f16(af, bf[nt], acc[nt],
                                                         0, 0, 0);
    }
    __syncthreads();
  }

  // ---- epilogue: sxp tile -> LDS (fp16, padded stride 72).
  // C/D layout: col = lane&15 (n), row = quad*4 + reg (m/j)
#pragma unroll
  for (int nt = 0; nt < 2; nt++)
#pragma unroll
    for (int r = 0; r < 4; r++) {
      const int jl = wm * 16 + quad * 4 + r;
      const int nl = wn * 32 + nt * 16 + m16;
      Sx[jl * 72 + nl] = (_Float16)acc[nt][r];
    }
  __syncthreads();

  // ---- fused partial score: thread t -> j = t&31, b-group = t>>5 (4 b's).
  // Half-wave shares b-group -> Xl reads are 2-address broadcasts (free).
  const int j = tid & 31;
  const int bg = tid >> 5;
  float dotb[4] = {0.f, 0.f, 0.f, 0.f};
  float rsq = 0.f;
#pragma unroll
  for (int c = 0; c < 8; c++) {
    const f16x8 hv = *(const f16x8*)&Sx[j * 72 + c * 8];
    const f16x2* hp = (const f16x2*)&hv;
#pragma unroll
    for (int i = 0; i < 4; i++)
      rsq = __builtin_amdgcn_fdot2(hp[i], hp[i], rsq, false);
#pragma unroll
    for (int b4 = 0; b4 < 4; b4++) {
      const f16x8 xv = *(const f16x8*)&Xl[(bg * 4 + b4) * 64 + c * 8];
      const f16x2* xp = (const f16x2*)&xv;
#pragma unroll
      for (int i = 0; i < 4; i++)
        dotb[b4] = __builtin_amdgcn_fdot2(hp[i], xp[i], dotb[b4], false);
    }
  }
  // write-once partial stores (no atomics, no zero-init)
  float* __restrict__ outP = scP + (size_t)ntile * BATCH * NUM_SUPPORT;
#pragma unroll
  for (int b4 = 0; b4 < 4; b4++) {
    outP[(size_t)(bg * 4 + b4) * NUM_SUPPORT + bm + j] = dotb[b4] - rsq;
  }
}

// ---------------------------------------------------------------------------
// finish: per batch row: sum 4 partials, row max, exp, class bins, log.
// One block (1024 thr) per b; row values kept in registers between passes.
// ---------------------------------------------------------------------------
__global__ __launch_bounds__(1024) void finish_kernel(
    const float* __restrict__ scP, const int* __restrict__ sy,
    float* __restrict__ out) {
  __shared__ float cls[N_CLASSES];
  __shared__ float redm[16];
  __shared__ float reds[16];

  const int b = blockIdx.x;
  const int t = threadIdx.x;
  const int lane = t & 63, wave = t >> 6;
  const size_t P = (size_t)BATCH * NUM_SUPPORT;
  const float* __restrict__ row0 = scP + (size_t)b * NUM_SUPPORT;

  float v[8];
  float m = -1e30f;
#pragma unroll
  for (int jj = 0; jj < 8; jj++) {
    const size_t o = (size_t)jj * 1024 + t;
    v[jj] = (row0[o] + row0[P + o]) + (row0[2 * P + o] + row0[3 * P + o]);
    m = fmaxf(m, v[jj]);
  }
#pragma unroll
  for (int o = 1; o < 64; o <<= 1) m = fmaxf(m, __shfl_xor(m, o, 64));
  if (lane == 0) redm[wave] = m;
  if (t < N_CLASSES) cls[t] = 0.0f;
  __syncthreads();
  float gm = redm[0];
#pragma unroll
  for (int i = 1; i < 16; i++) gm = fmaxf(gm, redm[i]);

  float lsum = 0.0f;
#pragma unroll
  for (int jj = 0; jj < 8; jj++) {
    const float e = expf(v[jj] - gm);
    lsum += e;
    atomicAdd(&cls[sy[jj * 1024 + t]], e);
  }
#pragma unroll
  for (int o = 1; o < 64; o <<= 1) lsum += __shfl_xor(lsum, o, 64);
  if (lane == 0) reds[wave] = lsum;
  __syncthreads();
  float total = 0.f;
#pragma unroll
  for (int i = 0; i < 16; i++) total += reds[i];
  const float inv = 1.0f / total;
  if (t < N_CLASSES) {
    out[(size_t)b * N_CLASSES + t] = logf(cls[t] * inv + 1e-12f);
  }
}

// ---------------------------------------------------------------------------
extern "C" void kernel_launch(void* const* d_in, const int* in_sizes, int n_in,
                              void* d_out, int out_size, void* d_ws,
                              size_t ws_size, hipStream_t stream) {
  const float* x = (const float*)d_in[0];   // (32, 1024)
  const float* sx = (const float*)d_in[1];  // (8192, 1024)
  const float* W = (const float*)d_in[2];   // (1024, 256)
  const int* sy = (const int*)d_in[3];      // (8192,)
  float* out = (float*)d_out;               // (32, 1000)

  char* p = (char*)d_ws;
  float* scP = (float*)p;         p += (size_t)4 * BATCH * NUM_SUPPORT * 4;
  _Float16* W1 = (_Float16*)p;    p += (size_t)PROJ_DIM * FEAT_DIM * 2;
  _Float16* xqh2 = (_Float16*)p;  // 32*256*2

  prelude_kernel<<<dim3(PW_BLOCKS + PX_BLOCKS), dim3(256), 0, stream>>>(
      W, x, W1, xqh2);
  gemm_score_kernel<<<dim3(1024), dim3(256), 0, stream>>>(sx, W1, xqh2, scP);
  finish_kernel<<<dim3(BATCH), dim3(1024), 0, stream>>>(scP, sy, out);
}